// Round 1
// baseline (1070.550 us; speedup 1.0000x reference)
//
#include <hip/hip_runtime.h>

// BotRGCN 4-layer forward.
// Round 6: transform-first RGCN restructure.
//  - mean_r(x_src) @ W_r  ==  mean_r((x @ W_r)_src): compute h = x @ [rel_w|root_w]
//    (K=128, N=768) FIRST, then aggregate h per (node,rel) segment. Kills the
//    128 MB agg buffer round-trip per layer (write 25.6 MB instead of 128 MB).
//  - x is kept as bf16 hi/lo planes (split once at producer epilogues), so GEMM
//    A-staging is a pure 16B copy instead of per-chunk split8 VALU.
//  - RGCN GEMM: K=128 (4 chunks, 8 barriers/block vs 48), gridDim.y=6 relation
//    blocks sharing the A panel via L3.

#define N_NODES 50000
#define N_EDGES 800000
#define R_REL   5
#define NSEG    (N_NODES * R_REL)   // 250000
#define SCAN_BS 1024
#define SCAN_NB ((NSEG + SCAN_BS - 1) / SCAN_BS)   // 245

typedef __attribute__((ext_vector_type(8))) short bf16x8;
typedef __attribute__((ext_vector_type(4))) short bf16x4;
typedef __attribute__((ext_vector_type(4))) float f32x4;

__device__ __forceinline__ float lrelu(float v) { return v > 0.f ? v : 0.01f * v; }

__device__ __forceinline__ unsigned short f2bf_rne(float f) {
    unsigned u = __float_as_uint(f);
    return (unsigned short)((u + 0x7fff + ((u >> 16) & 1)) >> 16);
}

// exact-ish split: hi = trunc-bf16(f), lo = rne-bf16(f - hi)
__device__ __forceinline__ void split1(float f, short& h, short& l) {
    unsigned u = __float_as_uint(f);
    unsigned short hh = (unsigned short)(u >> 16);
    h = (short)hh;
    l = (short)f2bf_rne(f - __uint_as_float((unsigned)hh << 16));
}

__device__ __forceinline__ void split8(const float* f, bf16x8& hi, bf16x8& lo) {
#pragma unroll
    for (int i = 0; i < 8; i++) {
        short h, l;
        split1(f[i], h, l);
        hi[i] = h;
        lo[i] = l;
    }
}

// ---------------- CSR build ----------------
__global__ __launch_bounds__(256) void count_kernel(const int* __restrict__ ei,
                                                    const int* __restrict__ et,
                                                    int* __restrict__ cnt) {
    int e = blockIdx.x * 256 + threadIdx.x;
    if (e >= N_EDGES) return;
    atomicAdd(&cnt[ei[N_EDGES + e] * R_REL + et[e]], 1);
}

__global__ __launch_bounds__(SCAN_BS) void scan1(const int* __restrict__ cnt,
                                                 int* __restrict__ rowptr,
                                                 int* __restrict__ blockSums) {
    __shared__ int s[SCAN_BS];
    int t = threadIdx.x;
    int i = blockIdx.x * SCAN_BS + t;
    int v = (i < NSEG) ? cnt[i] : 0;
    s[t] = v;
    __syncthreads();
#pragma unroll
    for (int off = 1; off < SCAN_BS; off <<= 1) {
        int add = (t >= off) ? s[t - off] : 0;
        __syncthreads();
        s[t] += add;
        __syncthreads();
    }
    if (i < NSEG) rowptr[i] = s[t] - v;
    if (t == SCAN_BS - 1) blockSums[blockIdx.x] = s[t];
}

__global__ __launch_bounds__(256) void scan2(int* __restrict__ blockSums) {
    __shared__ int s[256];
    int t = threadIdx.x;
    int v = (t < SCAN_NB) ? blockSums[t] : 0;
    s[t] = v;
    __syncthreads();
#pragma unroll
    for (int off = 1; off < 256; off <<= 1) {
        int add = (t >= off) ? s[t - off] : 0;
        __syncthreads();
        s[t] += add;
        __syncthreads();
    }
    if (t < SCAN_NB) blockSums[t] = s[t] - v;
}

__global__ __launch_bounds__(SCAN_BS) void scan3(int* __restrict__ rowptr,
                                                 const int* __restrict__ blockSums) {
    int i = blockIdx.x * SCAN_BS + threadIdx.x;
    if (i == 0) rowptr[NSEG] = N_EDGES;
    if (i < NSEG) rowptr[i] += blockSums[blockIdx.x];
}

__global__ __launch_bounds__(256) void fill_kernel(const int* __restrict__ ei,
                                                   const int* __restrict__ et,
                                                   const int* __restrict__ rowptr,
                                                   int* __restrict__ cursor,
                                                   int* __restrict__ srcSorted) {
    int e = blockIdx.x * 256 + threadIdx.x;
    if (e >= N_EDGES) return;
    int seg = ei[N_EDGES + e] * R_REL + et[e];
    int pos = atomicAdd(&cursor[seg], 1);
    srcSorted[rowptr[seg] + pos] = ei[e];
}

// ---------------- weight prep: fp32 W[K][NC] (k-major) -> swizzled fragments ----------------
// out layout: [chunk][plane(hi=0,lo=1)][nt][lane(64)][8]  (shorts)
// fragment value for (c, nt, lane l, j): W[k= c*32 + (l>>4)*8 + j][n= nt*16 + (l&15)]
__global__ __launch_bounds__(256) void build_bswz(const float* __restrict__ W,
                                                  int K, int NC, int NTILES,
                                                  short* __restrict__ out) {
    int tid = blockIdx.x * 256 + threadIdx.x;
    int total = (K / 32) * NTILES * 64;
    if (tid >= total) return;
    int l  = tid & 63;
    int nt = (tid >> 6) % NTILES;
    int c  = tid / (64 * NTILES);
    int n = nt * 16 + (l & 15);
    int k0 = c * 32 + (l >> 4) * 8;
    float f[8];
#pragma unroll
    for (int j = 0; j < 8; j++) f[j] = W[(size_t)(k0 + j) * NC + n];
    bf16x8 hi, lo;
    split8(f, hi, lo);
    size_t base = (size_t)c * (2 * NTILES * 512);
    *(bf16x8*)(out + base + ((size_t)nt * 64 + l) * 8) = hi;
    *(bf16x8*)(out + base + (size_t)NTILES * 512 + ((size_t)nt * 64 + l) * 8) = lo;
}

// ---------------- fused aggregate: out[n] = sum_r mean_seg h[src][r*128..] + h[n][640..] + b
// then split to bf16 hi/lo planes (next layer's A operand).
__global__ __launch_bounds__(256) void agg2_kernel(const float* __restrict__ hbuf,
                                                   const int* __restrict__ rowptr,
                                                   const int* __restrict__ srcSorted,
                                                   const float* __restrict__ rgcn_b,
                                                   short* __restrict__ xh,
                                                   short* __restrict__ xl) {
    int t = blockIdx.x * 256 + threadIdx.x;
    int node = t >> 5;
    if (node >= N_NODES) return;
    int lane = t & 31;
    float4 acc = ((const float4*)(hbuf + (size_t)node * 768 + 640))[lane];  // root slice
    float4 bv = ((const float4*)rgcn_b)[lane];
    acc.x += bv.x; acc.y += bv.y; acc.z += bv.z; acc.w += bv.w;
    int base = node * R_REL;
    int beg = rowptr[base];
    for (int r = 0; r < R_REL; r++) {
        int end = rowptr[base + r + 1];
        int c = end - beg;
        if (c > 0) {
            float sx = 0.f, sy = 0.f, sz = 0.f, sw = 0.f;
            int i = beg;
            // 2-way unroll: two independent gathers in flight per iteration
            for (; i + 1 < end; i += 2) {
                int s0 = srcSorted[i];
                int s1 = srcSorted[i + 1];
                float4 v0 = ((const float4*)(hbuf + (size_t)s0 * 768 + r * 128))[lane];
                float4 v1 = ((const float4*)(hbuf + (size_t)s1 * 768 + r * 128))[lane];
                sx += v0.x + v1.x; sy += v0.y + v1.y;
                sz += v0.z + v1.z; sw += v0.w + v1.w;
            }
            if (i < end) {
                int s0 = srcSorted[i];
                float4 v0 = ((const float4*)(hbuf + (size_t)s0 * 768 + r * 128))[lane];
                sx += v0.x; sy += v0.y; sz += v0.z; sw += v0.w;
            }
            float inv = 1.0f / (float)c;
            acc.x += inv * sx; acc.y += inv * sy;
            acc.z += inv * sz; acc.w += inv * sw;
        }
        beg = end;
    }
    float f[4] = {acc.x, acc.y, acc.z, acc.w};
    bf16x4 hv, lv;
#pragma unroll
    for (int j = 0; j < 4; j++) {
        short hh, ll;
        split1(f[j], hh, ll);
        hv[j] = hh; lv[j] = ll;
    }
    *(bf16x4*)(xh + (size_t)node * 128 + lane * 4) = hv;
    *(bf16x4*)(xl + (size_t)node * 128 + lane * 4) = lv;
}

// ---------------- MFMA bf16x3 GEMM, fp32 A (des/tweet encoders only) ----------------
// C planes (hi/lo) [M][128], cols [colofs, colofs+NT*16), lrelu applied.
template <int NT>
__global__ __launch_bounds__(256) void mfma_gemm_f32s(const float* __restrict__ A, int K,
                                                      const short* __restrict__ Bswz,
                                                      const float* __restrict__ bias,
                                                      short* __restrict__ Ch,
                                                      short* __restrict__ Cl,
                                                      int M, int colofs) {
    constexpr int NH = NT / 2;
    __shared__ short Ahi[2048], Alo[2048];
    __shared__ short Bs[NT * 1024];
    const int t = threadIdx.x;
    const int m0 = blockIdx.x * 64;
    const int w = t >> 6, l = t & 63;
    const int q = l >> 4, ln = l & 15;
    const int mw = w >> 1, nw = w & 1;

    f32x4 acc[2][NH];
#pragma unroll
    for (int mt = 0; mt < 2; mt++)
#pragma unroll
        for (int nt = 0; nt < NH; nt++) acc[mt][nt] = (f32x4)0.f;

    const int nchunks = K / 32;
    const int r = t >> 2, qq = t & 3;
    const int aidx = (r >> 4) * 512 + qq * 128 + (r & 15) * 8;
    int gr = m0 + r; if (gr >= M) gr = M - 1;

    for (int c = 0; c < nchunks; c++) {
        __syncthreads();
        {
            const float* ap = A + (size_t)gr * K + c * 32 + qq * 8;
            float f[8];
            *(float4*)&f[0] = ((const float4*)ap)[0];
            *(float4*)&f[4] = ((const float4*)ap)[1];
            bf16x8 h0, l0;
            split8(f, h0, l0);
            *(bf16x8*)&Ahi[aidx] = h0;
            *(bf16x8*)&Alo[aidx] = l0;
        }
        {
            const short* gb = Bswz + (size_t)c * (NT * 1024);
#pragma unroll
            for (int i = 0; i < NH; i++) {
                int idx = i * 256 + t;
                *(bf16x8*)&Bs[idx * 8] = *(const bf16x8*)(gb + (size_t)idx * 8);
            }
        }
        __syncthreads();

        bf16x8 a_hi[2], a_lo[2];
#pragma unroll
        for (int mt = 0; mt < 2; mt++) {
            a_hi[mt] = *(const bf16x8*)&Ahi[(mw * 2 + mt) * 512 + l * 8];
            a_lo[mt] = *(const bf16x8*)&Alo[(mw * 2 + mt) * 512 + l * 8];
        }
#pragma unroll
        for (int nt = 0; nt < NH; nt++) {
            int ng = nw * NH + nt;
            bf16x8 bh = *(const bf16x8*)&Bs[(ng * 64 + l) * 8];
            bf16x8 bl = *(const bf16x8*)&Bs[NT * 512 + (ng * 64 + l) * 8];
#pragma unroll
            for (int mt = 0; mt < 2; mt++) {
                acc[mt][nt] = __builtin_amdgcn_mfma_f32_16x16x32_bf16(a_hi[mt], bh, acc[mt][nt], 0, 0, 0);
                acc[mt][nt] = __builtin_amdgcn_mfma_f32_16x16x32_bf16(a_hi[mt], bl, acc[mt][nt], 0, 0, 0);
                acc[mt][nt] = __builtin_amdgcn_mfma_f32_16x16x32_bf16(a_lo[mt], bh, acc[mt][nt], 0, 0, 0);
            }
        }
    }

#pragma unroll
    for (int nt = 0; nt < NH; nt++) {
        int ng = nw * NH + nt;
        int col = colofs + ng * 16 + ln;
        float bvv = bias[ng * 16 + ln];
#pragma unroll
        for (int mt = 0; mt < 2; mt++) {
            f32x4 v = acc[mt][nt];
#pragma unroll
            for (int i = 0; i < 4; i++) {
                int m = m0 + (mw * 2 + mt) * 16 + q * 4 + i;
                if (m < M) {
                    float xv = lrelu(v[i] + bvv);
                    short hh, ll;
                    split1(xv, hh, ll);
                    Ch[(size_t)m * 128 + col] = hh;
                    Cl[(size_t)m * 128 + col] = ll;
                }
            }
        }
    }
}

// ---------------- MFMA bf16x3 GEMM, pre-split bf16 A planes, K=128 ----------------
// A = (Ah, Al) [M][128] shorts. B block selected by blockIdx.y (stride bystride shorts),
// colofs = colofs0 + blockIdx.y*NT*16. Output either fp32 Cf[M][ldc] or split planes.
template <int NT, bool ACT, bool CSPLIT>
__global__ __launch_bounds__(256) void mfma_gemm_b(const short* __restrict__ Ah,
                                                   const short* __restrict__ Al,
                                                   const short* __restrict__ Bbase,
                                                   size_t bystride,
                                                   const float* __restrict__ bias,
                                                   float* __restrict__ Cf,
                                                   short* __restrict__ Ch,
                                                   short* __restrict__ Cl,
                                                   int M, int ldc, int colofs0) {
    constexpr int NH = NT / 2;
    __shared__ short Ahs[2048], Als[2048];
    __shared__ short Bs[NT * 1024];
    const int t = threadIdx.x;
    const int m0 = blockIdx.x * 64;
    const int colofs = colofs0 + blockIdx.y * (NT * 16);
    const short* Bb = Bbase + (size_t)blockIdx.y * bystride;
    const int w = t >> 6, l = t & 63;
    const int q = l >> 4, ln = l & 15;
    const int mw = w >> 1, nw = w & 1;

    f32x4 acc[2][NH];
#pragma unroll
    for (int mt = 0; mt < 2; mt++)
#pragma unroll
        for (int nt = 0; nt < NH; nt++) acc[mt][nt] = (f32x4)0.f;

    const int r = t >> 2, qq = t & 3;
    const int aidx = (r >> 4) * 512 + qq * 128 + (r & 15) * 8;
    int gr = m0 + r; if (gr >= M) gr = M - 1;
    const size_t aofs = (size_t)gr * 128 + qq * 8;   // shorts, K = 128

    for (int c = 0; c < 4; c++) {
        __syncthreads();
        // stage A: pure copies (split already done at producer)
        *(bf16x8*)&Ahs[aidx] = *(const bf16x8*)(Ah + aofs + c * 32);
        *(bf16x8*)&Als[aidx] = *(const bf16x8*)(Al + aofs + c * 32);
        // stage B: flat coalesced copy of NT*1024 shorts
        {
            const short* gb = Bb + (size_t)c * (NT * 1024);
#pragma unroll
            for (int i = 0; i < NH; i++) {
                int idx = i * 256 + t;
                *(bf16x8*)&Bs[idx * 8] = *(const bf16x8*)(gb + (size_t)idx * 8);
            }
        }
        __syncthreads();

        bf16x8 a_hi[2], a_lo[2];
#pragma unroll
        for (int mt = 0; mt < 2; mt++) {
            a_hi[mt] = *(const bf16x8*)&Ahs[(mw * 2 + mt) * 512 + l * 8];
            a_lo[mt] = *(const bf16x8*)&Als[(mw * 2 + mt) * 512 + l * 8];
        }
#pragma unroll
        for (int nt = 0; nt < NH; nt++) {
            int ng = nw * NH + nt;
            bf16x8 bh = *(const bf16x8*)&Bs[(ng * 64 + l) * 8];
            bf16x8 bl = *(const bf16x8*)&Bs[NT * 512 + (ng * 64 + l) * 8];
#pragma unroll
            for (int mt = 0; mt < 2; mt++) {
                acc[mt][nt] = __builtin_amdgcn_mfma_f32_16x16x32_bf16(a_hi[mt], bh, acc[mt][nt], 0, 0, 0);
                acc[mt][nt] = __builtin_amdgcn_mfma_f32_16x16x32_bf16(a_hi[mt], bl, acc[mt][nt], 0, 0, 0);
                acc[mt][nt] = __builtin_amdgcn_mfma_f32_16x16x32_bf16(a_lo[mt], bh, acc[mt][nt], 0, 0, 0);
            }
        }
    }

#pragma unroll
    for (int nt = 0; nt < NH; nt++) {
        int ng = nw * NH + nt;
        int col = colofs + ng * 16 + ln;
        float bvv = bias ? bias[ng * 16 + ln] : 0.f;
#pragma unroll
        for (int mt = 0; mt < 2; mt++) {
            f32x4 v = acc[mt][nt];
#pragma unroll
            for (int i = 0; i < 4; i++) {
                int m = m0 + (mw * 2 + mt) * 16 + q * 4 + i;
                if (m < M) {
                    float xv = v[i] + bvv;
                    if (ACT) xv = lrelu(xv);
                    if (CSPLIT) {
                        short hh, ll;
                        split1(xv, hh, ll);
                        Ch[(size_t)m * 128 + col] = hh;
                        Cl[(size_t)m * 128 + col] = ll;
                    } else {
                        Cf[(size_t)m * ldc + col] = xv;
                    }
                }
            }
        }
    }
}

// ---------------- small feature encoders (K=6, K=11) -> split planes ----------------
__global__ __launch_bounds__(256) void encode_small(const float* __restrict__ num_prop,
                                                    const float* __restrict__ cat_prop,
                                                    const float* __restrict__ W_np,
                                                    const float* __restrict__ b_np,
                                                    const float* __restrict__ W_cp,
                                                    const float* __restrict__ b_cp,
                                                    short* __restrict__ xh,
                                                    short* __restrict__ xl) {
    int t = blockIdx.x * 256 + threadIdx.x;
    int node = t >> 6;
    int jj = t & 63;
    if (node >= N_NODES) return;
    float acc;
    int col;
    if (jj < 32) {
        acc = b_np[jj];
        const float* row = num_prop + (size_t)node * 6;
#pragma unroll
        for (int k = 0; k < 6; k++) acc = fmaf(row[k], W_np[k * 32 + jj], acc);
        col = 64 + jj;
    } else {
        int j = jj - 32;
        acc = b_cp[j];
        const float* row = cat_prop + (size_t)node * 11;
#pragma unroll
        for (int k = 0; k < 11; k++) acc = fmaf(row[k], W_cp[k * 32 + j], acc);
        col = 96 + j;
    }
    float xv = lrelu(acc);
    short hh, ll;
    split1(xv, hh, ll);
    xh[(size_t)node * 128 + col] = hh;
    xl[(size_t)node * 128 + col] = ll;
}

// ---------------- final projection 128 -> 2 ----------------
__global__ __launch_bounds__(256) void out_proj(const float* __restrict__ X,
                                                const float* __restrict__ W,
                                                const float* __restrict__ b,
                                                float* __restrict__ out, int M) {
    int n = blockIdx.x * 256 + threadIdx.x;
    if (n >= M) return;
    float a0 = b[0], a1 = b[1];
    const float4* xr = (const float4*)(X + (size_t)n * 128);
#pragma unroll
    for (int k4 = 0; k4 < 32; k4++) {
        float4 v = xr[k4];
        a0 = fmaf(v.x, W[(k4 * 4 + 0) * 2 + 0], a0);
        a1 = fmaf(v.x, W[(k4 * 4 + 0) * 2 + 1], a1);
        a0 = fmaf(v.y, W[(k4 * 4 + 1) * 2 + 0], a0);
        a1 = fmaf(v.y, W[(k4 * 4 + 1) * 2 + 1], a1);
        a0 = fmaf(v.z, W[(k4 * 4 + 2) * 2 + 0], a0);
        a1 = fmaf(v.z, W[(k4 * 4 + 2) * 2 + 1], a1);
        a0 = fmaf(v.w, W[(k4 * 4 + 3) * 2 + 0], a0);
        a1 = fmaf(v.w, W[(k4 * 4 + 3) * 2 + 1], a1);
    }
    out[(size_t)n * 2 + 0] = a0;
    out[(size_t)n * 2 + 1] = a1;
}

static inline size_t align64(size_t x) { return (x + 63) & ~(size_t)63; }

extern "C" void kernel_launch(void* const* d_in, const int* in_sizes, int n_in,
                              void* d_out, int out_size, void* d_ws, size_t ws_size,
                              hipStream_t stream) {
    const float* des      = (const float*)d_in[0];
    const float* tweet    = (const float*)d_in[1];
    const float* num_prop = (const float*)d_in[2];
    const float* cat_prop = (const float*)d_in[3];
    const int*   edge_index = (const int*)d_in[4];
    const int*   edge_type  = (const int*)d_in[5];
    const float* W_des = (const float*)d_in[6];  const float* b_des = (const float*)d_in[7];
    const float* W_tw  = (const float*)d_in[8];  const float* b_tw  = (const float*)d_in[9];
    const float* W_np  = (const float*)d_in[10]; const float* b_np  = (const float*)d_in[11];
    const float* W_cp  = (const float*)d_in[12]; const float* b_cp  = (const float*)d_in[13];
    const float* W_in  = (const float*)d_in[14]; const float* b_in  = (const float*)d_in[15];
    const float* rel_w = (const float*)d_in[16]; const float* root_w = (const float*)d_in[17];
    const float* rgcn_b = (const float*)d_in[18];
    const float* W_o1  = (const float*)d_in[19]; const float* b_o1  = (const float*)d_in[20];
    const float* W_o2  = (const float*)d_in[21]; const float* b_o2  = (const float*)d_in[22];
    float* out = (float*)d_out;

    // workspace layout
    char* p = (char*)d_ws;
    float* h    = (float*)p;           p += (size_t)N_NODES * 768 * 4;   // 153.6 MB
    short* xhA  = (short*)p;           p += (size_t)N_NODES * 128 * 2;
    short* xlA  = (short*)p;           p += (size_t)N_NODES * 128 * 2;
    short* xhB  = (short*)p;           p += (size_t)N_NODES * 128 * 2;
    short* xlB  = (short*)p;           p += (size_t)N_NODES * 128 * 2;
    int* cnt       = (int*)p;          p += (size_t)NSEG * 4;
    int* rowptr    = (int*)p;          p += (size_t)(NSEG + 1) * 4;
    int* cursor    = (int*)p;          p += (size_t)NSEG * 4;
    int* srcSorted = (int*)p;          p += (size_t)N_EDGES * 4;
    int* blockSums = (int*)p;          p += (size_t)256 * 4;
    p = (char*)align64((size_t)p);
    // swizzled weights (shorts)
    short* bz_cat = (short*)p;         p += (size_t)6 * 32768 * 2;   // 5 rel + root, each 4 chunks
    short* bz_in  = (short*)p;         p += (size_t)32768 * 2;
    short* bz_o1  = (short*)p;         p += (size_t)32768 * 2;
    short* bz_des = (short*)p;         p += (size_t)24 * 2048 * 2;
    short* bz_tw  = (short*)p;         p += (size_t)24 * 2048 * 2;

    // 0. weight prep
    for (int r = 0; r < R_REL; r++)
        build_bswz<<<8, 256, 0, stream>>>(rel_w + (size_t)r * 128 * 128, 128, 128, 8,
                                          bz_cat + (size_t)r * 32768);
    build_bswz<<<8, 256, 0, stream>>>(root_w, 128, 128, 8, bz_cat + (size_t)5 * 32768);
    build_bswz<<<8, 256, 0, stream>>>(W_in, 128, 128, 8, bz_in);
    build_bswz<<<8, 256, 0, stream>>>(W_o1, 128, 128, 8, bz_o1);
    build_bswz<<<12, 256, 0, stream>>>(W_des, 768, 32, 2, bz_des);
    build_bswz<<<12, 256, 0, stream>>>(W_tw, 768, 32, 2, bz_tw);

    // 1. CSR build (layer-invariant)
    hipMemsetAsync(cnt, 0, (size_t)NSEG * sizeof(int), stream);
    hipMemsetAsync(cursor, 0, (size_t)NSEG * sizeof(int), stream);
    count_kernel<<<(N_EDGES + 255) / 256, 256, 0, stream>>>(edge_index, edge_type, cnt);
    scan1<<<SCAN_NB, SCAN_BS, 0, stream>>>(cnt, rowptr, blockSums);
    scan2<<<1, 256, 0, stream>>>(blockSums);
    scan3<<<SCAN_NB, SCAN_BS, 0, stream>>>(rowptr, blockSums);
    fill_kernel<<<(N_EDGES + 255) / 256, 256, 0, stream>>>(
        edge_index, edge_type, rowptr, cursor, srcSorted);

    const int gm = (N_NODES + 63) / 64;   // 782

    // 2. encode -> xA planes
    encode_small<<<(N_NODES * 64 + 255) / 256, 256, 0, stream>>>(
        num_prop, cat_prop, W_np, b_np, W_cp, b_cp, xhA, xlA);
    mfma_gemm_f32s<2><<<gm, 256, 0, stream>>>(des, 768, bz_des, b_des, xhA, xlA, N_NODES, 0);
    mfma_gemm_f32s<2><<<gm, 256, 0, stream>>>(tweet, 768, bz_tw, b_tw, xhA, xlA, N_NODES, 32);

    // 3. input linear: xA -> xB planes
    mfma_gemm_b<8, true, true><<<gm, 256, 0, stream>>>(
        xhA, xlA, bz_in, 0, b_in, nullptr, xhB, xlB, N_NODES, 128, 0);

    // 4. RGCN x4 (transform-first)
    short *curh = xhB, *curl = xlB, *nxth = xhA, *nxtl = xlA;
    for (int lyr = 0; lyr < 4; lyr++) {
        dim3 grgcn(gm, 6);
        mfma_gemm_b<8, false, false><<<grgcn, 256, 0, stream>>>(
            curh, curl, bz_cat, 32768, nullptr, h, nullptr, nullptr, N_NODES, 768, 0);
        agg2_kernel<<<(N_NODES * 32 + 255) / 256, 256, 0, stream>>>(
            h, rowptr, srcSorted, rgcn_b, nxth, nxtl);
        short* th = curh; curh = nxth; nxth = th;
        short* tl = curl; curl = nxtl; nxtl = tl;
    }

    // 5. output head: x -> h[:, :128] fp32 -> out
    mfma_gemm_b<8, true, false><<<gm, 256, 0, stream>>>(
        curh, curl, bz_o1, 0, b_o1, h, nullptr, nullptr, N_NODES, 128, 0);
    out_proj<<<(N_NODES + 255) / 256, 256, 0, stream>>>(h, W_o2, b_o2, out, N_NODES);
}